// Round 6
// baseline (135.444 us; speedup 1.0000x reference)
//
#include <hip/hip_runtime.h>
#include <hip/hip_bf16.h>
#include <stdint.h>

#define NROWS 4096
#define CDIM  512
#define TOPK  5
#define BMJ   128   // prob2 (j) rows per block
#define BNI   256   // prob1 (i) rows per block
#define BK    32
#define NKT   16    // CDIM / BK
#define REP   8     // DIAGNOSTIC: repeat K-sweep 8x; epilogue divides by 8 (exact)

typedef __bf16 bf16x8 __attribute__((ext_vector_type(8)));
typedef float  f32x4  __attribute__((ext_vector_type(4)));
typedef unsigned long long u64;

// slot swizzle: rows 0..15 cover every 16B bank-granule group exactly twice (2-way = free)
__device__ __forceinline__ int swz(int row) { return (row ^ (row >> 2)) & 3; }

// ---------------- kernel A: prep = bf16 convert (K-tiled + swizzled) + top-5 keys ----
__global__ __launch_bounds__(256) void
prep_kernel(const float* __restrict__ p1, const float* __restrict__ p2,
            const float* __restrict__ feat1,
            __bf16* __restrict__ o1, __bf16* __restrict__ o2,
            u64* __restrict__ keys) {
  const int bid = blockIdx.x, tid = threadIdx.x;
  if (bid < 2048) {
    const int arr = bid >> 10;            // 0: p1->o1, 1: p2->o2
    const int b2  = bid & 1023;
    const int kt  = b2 >> 6;
    const int c   = (b2 & 63) * 256 + tid;  // row*4 + slot
    const int row = c >> 2;
    const int s   = c & 3;
    const float* src = (arr ? p2 : p1) + (size_t)row * CDIM + kt * 32 + s * 8;
    __bf16*      dst = (arr ? o2 : o1) + ((size_t)kt * NROWS + row) * 32 + ((s ^ swz(row)) * 8);
    const float4 a = *(const float4*)src;
    const float4 b = *(const float4*)(src + 4);
    bf16x8 v;
    v[0]=(__bf16)a.x; v[1]=(__bf16)a.y; v[2]=(__bf16)a.z; v[3]=(__bf16)a.w;
    v[4]=(__bf16)b.x; v[5]=(__bf16)b.y; v[6]=(__bf16)b.z; v[7]=(__bf16)b.w;
    *(bf16x8*)dst = v;
  } else {
    const int row = (bid - 2048) * 4 + (tid >> 6);
    const int l   = tid & 63;
    const float* r = feat1 + (size_t)row * CDIM;
    float v[8];
    const float4 a = *(const float4*)(r + l * 8);
    const float4 b = *(const float4*)(r + l * 8 + 4);
    v[0]=a.x; v[1]=a.y; v[2]=a.z; v[3]=a.w;
    v[4]=b.x; v[5]=b.y; v[6]=b.z; v[7]=b.w;

    int sel[TOPK];
#pragma unroll
    for (int s = 0; s < TOPK; ++s) {
      float bv = -__builtin_inff();
      int   bi = 0x7fffffff;
#pragma unroll
      for (int t = 0; t < 8; ++t)
        if (v[t] > bv) { bv = v[t]; bi = l * 8 + t; }   // strict > : smallest idx on tie
#pragma unroll
      for (int off = 32; off > 0; off >>= 1) {
        float ov = __shfl_xor(bv, off);
        int   oi = __shfl_xor(bi, off);
        if (ov > bv || (ov == bv && oi < bi)) { bv = ov; bi = oi; }
      }
      sel[s] = bi;
      const int loc = bi - l * 8;
      if (loc >= 0 && loc < 8) v[loc] = -__builtin_inff();
    }
#define CSWAP(x, y) { int mn = min(sel[x], sel[y]); int mx = max(sel[x], sel[y]); sel[x] = mn; sel[y] = mx; }
    CSWAP(0,1) CSWAP(3,4) CSWAP(2,4) CSWAP(2,3) CSWAP(1,4)
    CSWAP(0,3) CSWAP(0,2) CSWAP(1,3) CSWAP(1,2)
#undef CSWAP
    if (l == 0) {
      keys[row] = (u64)sel[0] | ((u64)sel[1] << 9) | ((u64)sel[2] << 18)
                | ((u64)sel[3] << 27) | ((u64)sel[4] << 36);
    }
  }
}

// ---------------- kernel B: fused GEMM + BCE, round-4 structure, REP x K-sweep ------
__global__ __launch_bounds__(512, 4) void
gemm_loss_kernel(const __bf16* __restrict__ o1k,   // prob1, K-tiled [kt][row][32]
                 const __bf16* __restrict__ o2k,   // prob2, K-tiled
                 const u64* __restrict__ keys,
                 float* __restrict__ partials) {
  __shared__ __bf16 smA[3][BMJ * BK];   // 3 x 8 KB  (prob2 / j)
  __shared__ __bf16 smB[3][BNI * BK];   // 3 x 16 KB (prob1 / i)
  __shared__ float  red[512];

  const int tid = threadIdx.x;
  const int l   = tid & 63, w = tid >> 6;
  const int wr  = w >> 2,  wc = w & 3;     // j-half, i-quarter
  const int lr  = l & 15,  kq = l >> 4;

  const int bid = blockIdx.x;
  const int x   = bid & 7, v = bid >> 3;   // XCD-chunked swizzle
  const int jt  = (x & 3) * 8 + (v & 7);
  const int it  = (x >> 2) * 8 + (v >> 3);
  const int jb  = jt * BMJ, ib = it * BNI;

  f32x4 acc[4][4] = {};

  const __bf16* gA0 = o2k + (size_t)jb * 32;
  const __bf16* gB0 = o1k + (size_t)ib * 32;

  auto stage = [&](int slot, int kt) {
    const size_t ko = (size_t)kt * NROWS * 32;
    __builtin_amdgcn_global_load_lds(
        (const __attribute__((address_space(1))) unsigned int*)(const void*)(gA0 + ko + tid * 8),
        (__attribute__((address_space(3))) unsigned int*)(void*)&smA[slot][w * 512], 16, 0, 0);
#pragma unroll
    for (int i = 0; i < 2; ++i) {
      __builtin_amdgcn_global_load_lds(
          (const __attribute__((address_space(1))) unsigned int*)(const void*)(gB0 + ko + (i * 512 + tid) * 8),
          (__attribute__((address_space(3))) unsigned int*)(void*)&smB[slot][i * 4096 + w * 512], 16, 0, 0);
    }
  };

  auto compute = [&](int slot) {
    bf16x8 af[4], bfr[4];
#pragma unroll
    for (int m = 0; m < 4; ++m) {
      const int r = wr * 64 + m * 16 + lr;           // 0..127
      af[m] = *(const bf16x8*)&smA[slot][r * 32 + (kq ^ swz(r)) * 8];
    }
#pragma unroll
    for (int n = 0; n < 4; ++n) {
      const int r = wc * 64 + n * 16 + lr;           // 0..255
      bfr[n] = *(const bf16x8*)&smB[slot][r * 32 + (kq ^ swz(r)) * 8];
    }
    __builtin_amdgcn_s_setprio(1);
#pragma unroll
    for (int m = 0; m < 4; ++m)
#pragma unroll
      for (int n = 0; n < 4; ++n)
        acc[m][n] = __builtin_amdgcn_mfma_f32_16x16x32_bf16(af[m], bfr[n], acc[m][n], 0, 0, 0);
    __builtin_amdgcn_s_setprio(0);
  };

  stage(0, 0);
  stage(1, 1);
  const int NV = NKT * REP;
  for (int vk = 0; vk < NV; ++vk) {
    if (vk == NV - 1) asm volatile("s_waitcnt vmcnt(0)" ::: "memory");
    else              asm volatile("s_waitcnt vmcnt(3)" ::: "memory");  // own vk-loads landed
    __builtin_amdgcn_s_barrier();
    __builtin_amdgcn_sched_barrier(0);
    if (vk + 2 < NV) stage((vk + 2) % 3, (vk + 2) & (NKT - 1));
    compute(vk % 3);
  }

  // ---- epilogue: BCE terms (acc/REP). C/D: col(i)=lane&15, row(j)=(lane>>4)*4+reg ----
  u64 ki[4];
#pragma unroll
  for (int n = 0; n < 4; ++n)
    ki[n] = keys[ib + wc * 64 + n * 16 + lr];

  float sum = 0.f;
#pragma unroll
  for (int m = 0; m < 4; ++m)
#pragma unroll
    for (int r = 0; r < 4; ++r) {
      const u64 kj = keys[jb + wr * 64 + m * 16 + kq * 4 + r];
#pragma unroll
      for (int n = 0; n < 4; ++n) {
        const float p = acc[m][n][r] * (1.0f / REP);
        const bool  t = (kj == ki[n]);
        const float xx = t ? p : (1.0f - p);
        sum += fmaxf(__logf(xx), -100.0f);
      }
    }

  red[tid] = sum;
  __syncthreads();
#pragma unroll
  for (int s = 256; s > 0; s >>= 1) {
    if (tid < s) red[tid] += red[tid + s];
    __syncthreads();
  }
  if (tid == 0) partials[bid] = red[0];
}

// ---------------- kernel C: deterministic finalize ----------------
__global__ void finalize_kernel(const float* __restrict__ partials,
                                float* __restrict__ out) {
  __shared__ float red[256];
  red[threadIdx.x] = partials[threadIdx.x] + partials[threadIdx.x + 256];
  __syncthreads();
  for (int st = 128; st > 0; st >>= 1) {
    if (threadIdx.x < st) red[threadIdx.x] += red[threadIdx.x + st];
    __syncthreads();
  }
  if (threadIdx.x == 0) out[0] = -red[0] * (1.0f / 16777216.0f);
}

extern "C" void kernel_launch(void* const* d_in, const int* in_sizes, int n_in,
                              void* d_out, int out_size, void* d_ws, size_t ws_size,
                              hipStream_t stream) {
  (void)in_sizes; (void)n_in; (void)out_size; (void)ws_size;
  const float* feat1 = (const float*)d_in[0];
  const float* prob1 = (const float*)d_in[2];
  const float* prob2 = (const float*)d_in[3];

  __bf16* o1 = (__bf16*)d_ws;
  __bf16* o2 = (__bf16*)((char*)d_ws + (size_t)NROWS * CDIM * 2);
  u64*   keys = (u64*)((char*)d_ws + (size_t)NROWS * CDIM * 4);
  float* partials = (float*)((char*)d_ws + (size_t)NROWS * CDIM * 4 + NROWS * 8);

  prep_kernel<<<3072, 256, 0, stream>>>(prob1, prob2, feat1, o1, o2, keys);
  gemm_loss_kernel<<<512, 512, 0, stream>>>(o1, o2, keys, partials);
  finalize_kernel<<<1, 256, 0, stream>>>(partials, (float*)d_out);
}

// Round 7
// 42.004 us; speedup vs baseline: 3.2246x; 3.2246x over previous
//
#include <hip/hip_runtime.h>
#include <hip/hip_bf16.h>
#include <stdint.h>

#define NROWS 4096
#define CDIM  512
#define TOPK  5
#define BMJ   128   // prob2 (j) rows per block
#define BNI   256   // prob1 (i) rows per block
#define BK    32
#define NKT   16    // CDIM / BK

typedef __bf16 bf16x8 __attribute__((ext_vector_type(8)));
typedef float  f32x4  __attribute__((ext_vector_type(4)));
typedef unsigned long long u64;

// slot swizzle: 16-lane b128 fragment reads hit each 16B granule exactly 2x (free)
__device__ __forceinline__ int swz(int row) { return (row ^ (row >> 2)) & 3; }

// ---------------- kernel A: prep = bf16 convert (K-tiled + swizzled) + top-5 keys ----
__global__ __launch_bounds__(256) void
prep_kernel(const float* __restrict__ p1, const float* __restrict__ p2,
            const float* __restrict__ feat1,
            __bf16* __restrict__ o1, __bf16* __restrict__ o2,
            u64* __restrict__ keys) {
  const int bid = blockIdx.x, tid = threadIdx.x;
  if (bid < 2048) {
    const int arr = bid >> 10;            // 0: p1->o1, 1: p2->o2
    const int b2  = bid & 1023;
    const int kt  = b2 >> 6;
    const int c   = (b2 & 63) * 256 + tid;  // row*4 + slot
    const int row = c >> 2;
    const int s   = c & 3;
    const float* src = (arr ? p2 : p1) + (size_t)row * CDIM + kt * 32 + s * 8;
    __bf16*      dst = (arr ? o2 : o1) + ((size_t)kt * NROWS + row) * 32 + ((s ^ swz(row)) * 8);
    const float4 a = *(const float4*)src;
    const float4 b = *(const float4*)(src + 4);
    bf16x8 v;
    v[0]=(__bf16)a.x; v[1]=(__bf16)a.y; v[2]=(__bf16)a.z; v[3]=(__bf16)a.w;
    v[4]=(__bf16)b.x; v[5]=(__bf16)b.y; v[6]=(__bf16)b.z; v[7]=(__bf16)b.w;
    *(bf16x8*)dst = v;
  } else {
    const int row = (bid - 2048) * 4 + (tid >> 6);
    const int l   = tid & 63;
    const float* r = feat1 + (size_t)row * CDIM;
    float v[8];
    const float4 a = *(const float4*)(r + l * 8);
    const float4 b = *(const float4*)(r + l * 8 + 4);
    v[0]=a.x; v[1]=a.y; v[2]=a.z; v[3]=a.w;
    v[4]=b.x; v[5]=b.y; v[6]=b.z; v[7]=b.w;

    int sel[TOPK];
#pragma unroll
    for (int s = 0; s < TOPK; ++s) {
      float bv = -__builtin_inff();
      int   bi = 0x7fffffff;
#pragma unroll
      for (int t = 0; t < 8; ++t)
        if (v[t] > bv) { bv = v[t]; bi = l * 8 + t; }   // strict > : smallest idx on tie
#pragma unroll
      for (int off = 32; off > 0; off >>= 1) {
        float ov = __shfl_xor(bv, off);
        int   oi = __shfl_xor(bi, off);
        if (ov > bv || (ov == bv && oi < bi)) { bv = ov; bi = oi; }
      }
      sel[s] = bi;
      const int loc = bi - l * 8;
      if (loc >= 0 && loc < 8) v[loc] = -__builtin_inff();
    }
#define CSWAP(x, y) { int mn = min(sel[x], sel[y]); int mx = max(sel[x], sel[y]); sel[x] = mn; sel[y] = mx; }
    CSWAP(0,1) CSWAP(3,4) CSWAP(2,4) CSWAP(2,3) CSWAP(1,4)
    CSWAP(0,3) CSWAP(0,2) CSWAP(1,3) CSWAP(1,2)
#undef CSWAP
    if (l == 0) {
      keys[row] = (u64)sel[0] | ((u64)sel[1] << 9) | ((u64)sel[2] << 18)
                | ((u64)sel[3] << 27) | ((u64)sel[4] << 36);
    }
  }
}

// ---------------- kernel B: fused GEMM + BCE ----------------
// 128(j) x 256(i) block tile, 256 thr = 4 waves (2x2), per-wave 64x128 = acc[4][8]
// (12 LDS reads per 32 MFMA = 0.375). 3-slot LDS rotation (72 KiB -> 2 blocks/CU),
// depth-2 prefetch with counted vmcnt(6), one barrier per K-step.
__global__ __launch_bounds__(256, 2) void
gemm_loss_kernel(const __bf16* __restrict__ o1k,   // prob1 (i), K-tiled [kt][row][32]
                 const __bf16* __restrict__ o2k,   // prob2 (j), K-tiled
                 const u64* __restrict__ keys,
                 float* __restrict__ partials) {
  __shared__ __bf16 smA[3][BMJ * BK];   // 3 x 8 KB  (prob2 / j)
  __shared__ __bf16 smB[3][BNI * BK];   // 3 x 16 KB (prob1 / i)
  __shared__ float  red[256];

  const int tid = threadIdx.x;
  const int l   = tid & 63, w = tid >> 6;      // 4 waves
  const int wr  = w >> 1,  wc = w & 1;         // j-half (64), i-half (128)
  const int lr  = l & 15,  kq = l >> 4;

  const int bid = blockIdx.x;
  const int x   = bid & 7, v = bid >> 3;       // XCD-chunked swizzle (512 blocks)
  const int jt  = (x & 3) * 8 + (v & 7);       // 0..31
  const int it  = (x >> 2) * 8 + (v >> 3);     // 0..15
  const int jb  = jt * BMJ, ib = it * BNI;

  f32x4 acc[4][8] = {};

  const __bf16* gA0 = o2k + (size_t)jb * 32;
  const __bf16* gB0 = o1k + (size_t)ib * 32;

  auto stage = [&](int slot, int kt) {          // 6 gload_lds per thread
    const size_t ko = (size_t)kt * NROWS * 32;
#pragma unroll
    for (int r = 0; r < 2; ++r)                 // A: 512 chunks
      __builtin_amdgcn_global_load_lds(
          (const __attribute__((address_space(1))) unsigned int*)(const void*)(gA0 + ko + (r * 256 + tid) * 8),
          (__attribute__((address_space(3))) unsigned int*)(void*)&smA[slot][(r * 256 + w * 64) * 8], 16, 0, 0);
#pragma unroll
    for (int r = 0; r < 4; ++r)                 // B: 1024 chunks
      __builtin_amdgcn_global_load_lds(
          (const __attribute__((address_space(1))) unsigned int*)(const void*)(gB0 + ko + (r * 256 + tid) * 8),
          (__attribute__((address_space(3))) unsigned int*)(void*)&smB[slot][(r * 256 + w * 64) * 8], 16, 0, 0);
  };

  auto compute = [&](int slot) {
    bf16x8 af[4], bfr[8];
#pragma unroll
    for (int m = 0; m < 4; ++m) {
      const int r = wr * 64 + m * 16 + lr;      // 0..127
      af[m] = *(const bf16x8*)&smA[slot][r * 32 + (kq ^ swz(r)) * 8];
    }
#pragma unroll
    for (int n = 0; n < 8; ++n) {
      const int r = wc * 128 + n * 16 + lr;     // 0..255
      bfr[n] = *(const bf16x8*)&smB[slot][r * 32 + (kq ^ swz(r)) * 8];
    }
    __builtin_amdgcn_s_setprio(1);
#pragma unroll
    for (int m = 0; m < 4; ++m)
#pragma unroll
      for (int n = 0; n < 8; ++n)
        acc[m][n] = __builtin_amdgcn_mfma_f32_16x16x32_bf16(af[m], bfr[n], acc[m][n], 0, 0, 0);
    __builtin_amdgcn_s_setprio(0);
  };

  stage(0, 0);
  stage(1, 1);
  for (int kt = 0; kt < NKT; ++kt) {
    if (kt == NKT - 1) asm volatile("s_waitcnt vmcnt(0)" ::: "memory");
    else               asm volatile("s_waitcnt vmcnt(6)" ::: "memory");  // own kt-tile landed
    __builtin_amdgcn_s_barrier();
    __builtin_amdgcn_sched_barrier(0);
    if (kt + 2 < NKT) stage((kt + 2) % 3, kt + 2);   // slot freed last iteration
    compute(kt % 3);
  }

  // ---- epilogue: BCE terms. C/D: col(i) = lane&15, row(j) = (lane>>4)*4 + reg ----
  u64 ki[8];
#pragma unroll
  for (int n = 0; n < 8; ++n)
    ki[n] = keys[ib + wc * 128 + n * 16 + lr];

  float sum = 0.f;
#pragma unroll
  for (int m = 0; m < 4; ++m)
#pragma unroll
    for (int r = 0; r < 4; ++r) {
      const u64 kj = keys[jb + wr * 64 + m * 16 + kq * 4 + r];
#pragma unroll
      for (int n = 0; n < 8; ++n) {
        const float p = acc[m][n][r];
        const bool  t = (kj == ki[n]);
        const float xx = t ? p : (1.0f - p);
        sum += fmaxf(__logf(xx), -100.0f);
      }
    }

  red[tid] = sum;
  __syncthreads();
#pragma unroll
  for (int s = 128; s > 0; s >>= 1) {
    if (tid < s) red[tid] += red[tid + s];
    __syncthreads();
  }
  if (tid == 0) partials[bid] = red[0];
}

// ---------------- kernel C: deterministic finalize ----------------
__global__ void finalize_kernel(const float* __restrict__ partials,
                                float* __restrict__ out) {
  __shared__ float red[256];
  red[threadIdx.x] = partials[threadIdx.x] + partials[threadIdx.x + 256];
  __syncthreads();
  for (int st = 128; st > 0; st >>= 1) {
    if (threadIdx.x < st) red[threadIdx.x] += red[threadIdx.x + st];
    __syncthreads();
  }
  if (threadIdx.x == 0) out[0] = -red[0] * (1.0f / 16777216.0f);
}

extern "C" void kernel_launch(void* const* d_in, const int* in_sizes, int n_in,
                              void* d_out, int out_size, void* d_ws, size_t ws_size,
                              hipStream_t stream) {
  (void)in_sizes; (void)n_in; (void)out_size; (void)ws_size;
  const float* feat1 = (const float*)d_in[0];
  const float* prob1 = (const float*)d_in[2];
  const float* prob2 = (const float*)d_in[3];

  __bf16* o1 = (__bf16*)d_ws;
  __bf16* o2 = (__bf16*)((char*)d_ws + (size_t)NROWS * CDIM * 2);
  u64*   keys = (u64*)((char*)d_ws + (size_t)NROWS * CDIM * 4);
  float* partials = (float*)((char*)d_ws + (size_t)NROWS * CDIM * 4 + NROWS * 8);

  prep_kernel<<<3072, 256, 0, stream>>>(prob1, prob2, feat1, o1, o2, keys);
  gemm_loss_kernel<<<512, 256, 0, stream>>>(o1, o2, keys, partials);
  finalize_kernel<<<1, 256, 0, stream>>>(partials, (float*)d_out);
}